// Round 1
// baseline (24967.944 us; speedup 1.0000x reference)
//
#include <hip/hip_runtime.h>
#include <hip/hip_bf16.h>

#define BB 128
#define SS 1000
#define II 128
#define HH 1024
#define G4 4096
#define KK (II + HH)   // 1152
#define NC 50

typedef __attribute__((ext_vector_type(8))) short short8v;
typedef __attribute__((ext_vector_type(4))) float f32x4;

static __device__ __forceinline__ short f2bf(float f) {
    union { float f; unsigned u; } v; v.f = f;
    unsigned u = v.u;
    u += 0x7FFFu + ((u >> 16) & 1u);   // RNE
    return (short)(u >> 16);
}

// ---------------------------------------------------------------------------
// Weight prep: Bt[n][k] (bf16, n = gate*1024 + j, k in [0,1152)) from fp32
// W_i*(k<128) / W_h*(k>=128). LDS-tiled transpose, coalesced on both sides.
// grid (36, 32, 4), block (32, 8)
// ---------------------------------------------------------------------------
__global__ void prep_weights(const float* __restrict__ Wx0, const float* __restrict__ Wx1,
                             const float* __restrict__ Wx2, const float* __restrict__ Wx3,
                             const float* __restrict__ Wh0, const float* __restrict__ Wh1,
                             const float* __restrict__ Wh2, const float* __restrict__ Wh3,
                             short* __restrict__ Bt) {
    __shared__ float lds[32][33];
    const int kt = blockIdx.x, jt = blockIdx.y, g = blockIdx.z;
    const int tx = threadIdx.x, ty = threadIdx.y;
    const float* Wx = (g == 0) ? Wx0 : (g == 1) ? Wx1 : (g == 2) ? Wx2 : Wx3;
    const float* Wh = (g == 0) ? Wh0 : (g == 1) ? Wh1 : (g == 2) ? Wh2 : Wh3;
    const int k0 = kt * 32, j0 = jt * 32;
#pragma unroll
    for (int r = 0; r < 4; r++) {
        int kk = k0 + ty + r * 8;
        float v = (kk < II) ? Wx[kk * HH + j0 + tx] : Wh[(kk - II) * HH + j0 + tx];
        lds[ty + r * 8][tx] = v;
    }
    __syncthreads();
#pragma unroll
    for (int r = 0; r < 4; r++) {
        int jj = ty + r * 8;
        Bt[(size_t)(g * HH + j0 + jj) * KK + k0 + tx] = f2bf(lds[tx][jj]);
    }
}

// ---------------------------------------------------------------------------
// Pack bias [4096] and zero-init c / h_bf16 / h_f32. grid 512, block 256.
// ---------------------------------------------------------------------------
__global__ void prep_misc(const float* __restrict__ bi, const float* __restrict__ bf_,
                          const float* __restrict__ bg, const float* __restrict__ bo,
                          float* __restrict__ b4, float* __restrict__ c,
                          short* __restrict__ hbf, float* __restrict__ hf) {
    int i = blockIdx.x * 256 + threadIdx.x;
    if (i < G4) {
        float v = (i < HH) ? bi[i] : (i < 2 * HH) ? bf_[i - HH]
                : (i < 3 * HH) ? bg[i - 2 * HH] : bo[i - 3 * HH];
        b4[i] = v;
    }
    if (i < BB * HH) { c[i] = 0.f; hbf[i] = 0; hf[i] = 0.f; }
}

// ---------------------------------------------------------------------------
// One LSTM timestep. grid 128 (= 2 batch-halves x 64 hidden-slices), block 256.
// Wave w handles batch rows [mh*64 + w*16, +16), hidden cols [j16*16, +16),
// all 4 gates -> elementwise update fully in-register.
// ---------------------------------------------------------------------------
__global__ __launch_bounds__(256) void lstm_step(
    const float* __restrict__ x, const short* __restrict__ Bt,
    const float* __restrict__ b4, float* __restrict__ c,
    short* __restrict__ hbf, float* __restrict__ hf, int t) {
    const int bid = blockIdx.x;
    const int mh = bid & 1;
    const int j16 = bid >> 1;
    const int tid = threadIdx.x;
    const int w = tid >> 6, l = tid & 63;
    const int lq = l >> 4, lr = l & 15;
    const int m0 = mh * 64 + w * 16;
    const int arow = m0 + lr;          // A-operand batch row for this lane
    const int j0 = j16 * 16;

    f32x4 acc0 = {0.f, 0.f, 0.f, 0.f}, acc1 = acc0, acc2 = acc0, acc3 = acc0;

    const short8v* hrow = (const short8v*)(hbf + (size_t)arow * HH);
    const float*   xrow = x + ((size_t)arow * SS + t) * II;
    const short8v* b0p = (const short8v*)(Bt + (size_t)(0 * HH + j0 + lr) * KK);
    const short8v* b1p = (const short8v*)(Bt + (size_t)(1 * HH + j0 + lr) * KK);
    const short8v* b2p = (const short8v*)(Bt + (size_t)(2 * HH + j0 + lr) * KK);
    const short8v* b3p = (const short8v*)(Bt + (size_t)(3 * HH + j0 + lr) * KK);

    // k-tiles 0..3: x part (fp32 -> bf16 on the fly)
#pragma unroll
    for (int kk = 0; kk < 4; kk++) {
        const float4* xp = (const float4*)(xrow + kk * 32 + lq * 8);
        float4 x0 = xp[0], x1 = xp[1];
        short8v a;
        a[0] = f2bf(x0.x); a[1] = f2bf(x0.y); a[2] = f2bf(x0.z); a[3] = f2bf(x0.w);
        a[4] = f2bf(x1.x); a[5] = f2bf(x1.y); a[6] = f2bf(x1.z); a[7] = f2bf(x1.w);
        const int bo_ = kk * 4 + lq;
        acc0 = __builtin_amdgcn_mfma_f32_16x16x32_bf16(a, b0p[bo_], acc0, 0, 0, 0);
        acc1 = __builtin_amdgcn_mfma_f32_16x16x32_bf16(a, b1p[bo_], acc1, 0, 0, 0);
        acc2 = __builtin_amdgcn_mfma_f32_16x16x32_bf16(a, b2p[bo_], acc2, 0, 0, 0);
        acc3 = __builtin_amdgcn_mfma_f32_16x16x32_bf16(a, b3p[bo_], acc3, 0, 0, 0);
    }
    // k-tiles 4..35: h part (bf16 direct)
#pragma unroll 4
    for (int kk = 4; kk < 36; kk++) {
        short8v a = hrow[(kk - 4) * 4 + lq];
        const int bo_ = kk * 4 + lq;
        acc0 = __builtin_amdgcn_mfma_f32_16x16x32_bf16(a, b0p[bo_], acc0, 0, 0, 0);
        acc1 = __builtin_amdgcn_mfma_f32_16x16x32_bf16(a, b1p[bo_], acc1, 0, 0, 0);
        acc2 = __builtin_amdgcn_mfma_f32_16x16x32_bf16(a, b2p[bo_], acc2, 0, 0, 0);
        acc3 = __builtin_amdgcn_mfma_f32_16x16x32_bf16(a, b3p[bo_], acc3, 0, 0, 0);
    }

    // epilogue: C/D mapping col = lane&15, row = (lane>>4)*4 + reg
    const int j = j0 + lr;
    const float bi = b4[j], bff = b4[HH + j], bg = b4[2 * HH + j], bo = b4[3 * HH + j];
#pragma unroll
    for (int r = 0; r < 4; r++) {
        const int bm = m0 + lq * 4 + r;
        float gi = acc0[r] + bi;
        float gf = acc1[r] + bff;
        float gg = acc2[r] + bg;
        float go = acc3[r] + bo;
        float si = 1.f / (1.f + __expf(-gi));
        float sf = 1.f / (1.f + __expf(-gf));
        float e2 = __expf(2.f * gg);
        float tg = 1.f - 2.f / (e2 + 1.f);
        float so = 1.f / (1.f + __expf(-go));
        size_t ci = (size_t)bm * HH + j;
        float cn = sf * c[ci] + si * tg;
        c[ci] = cn;
        float ec = __expf(2.f * cn);
        float tc = 1.f - 2.f / (ec + 1.f);
        float hh = so * tc;
        hbf[ci] = f2bf(hh);
        if (t == SS - 1) hf[ci] = hh;
    }
}

// ---------------------------------------------------------------------------
// out[b][o] = h[b] . W_out[o] + b_out[o].  grid 128 (b), block 256.
// ---------------------------------------------------------------------------
__global__ void final_linear(const float* __restrict__ hf, const float* __restrict__ Wout,
                             const float* __restrict__ bout, float* __restrict__ out) {
    __shared__ float hs[HH];
    const int b = blockIdx.x;
    for (int i = threadIdx.x; i < HH; i += 256) hs[i] = hf[(size_t)b * HH + i];
    __syncthreads();
    const int w = threadIdx.x >> 6, l = threadIdx.x & 63;
    for (int o = w; o < NC; o += 4) {
        float s = 0.f;
        const float* wr = Wout + (size_t)o * HH;
        for (int jj = l; jj < HH; jj += 64) s += hs[jj] * wr[jj];
#pragma unroll
        for (int d = 32; d > 0; d >>= 1) s += __shfl_down(s, d);
        if (l == 0) out[b * NC + o] = s + bout[o];
    }
}

extern "C" void kernel_launch(void* const* d_in, const int* in_sizes, int n_in,
                              void* d_out, int out_size, void* d_ws, size_t ws_size,
                              hipStream_t stream) {
    const float* x    = (const float*)d_in[0];
    const float* W_ii = (const float*)d_in[1];
    const float* W_hi = (const float*)d_in[2];
    const float* b_ii = (const float*)d_in[3];
    const float* W_if = (const float*)d_in[4];
    const float* W_hf = (const float*)d_in[5];
    const float* b_if = (const float*)d_in[6];
    const float* W_ig = (const float*)d_in[7];
    const float* W_hg = (const float*)d_in[8];
    const float* b_ig = (const float*)d_in[9];
    const float* W_io = (const float*)d_in[10];
    const float* W_ho = (const float*)d_in[11];
    const float* b_io = (const float*)d_in[12];
    const float* W_out = (const float*)d_in[13];
    const float* b_out = (const float*)d_in[14];

    char* ws = (char*)d_ws;
    short* Bt = (short*)ws;                         // 4096*1152*2 = 9,437,184 B
    float* b4 = (float*)(ws + 9437184);             // 16,384 B
    float* c  = (float*)(ws + 9437184 + 16384);     // 524,288 B
    short* hbf = (short*)(ws + 9437184 + 16384 + 524288);           // 262,144 B
    float* hf  = (float*)(ws + 9437184 + 16384 + 524288 + 262144);  // 524,288 B

    prep_weights<<<dim3(36, 32, 4), dim3(32, 8), 0, stream>>>(
        W_ii, W_if, W_ig, W_io, W_hi, W_hf, W_hg, W_ho, Bt);
    prep_misc<<<512, 256, 0, stream>>>(b_ii, b_if, b_ig, b_io, b4, c, hbf, hf);

    for (int t = 0; t < SS; t++)
        lstm_step<<<128, 256, 0, stream>>>(x, Bt, b4, c, hbf, hf, t);

    final_linear<<<BB, 256, 0, stream>>>(hf, W_out, b_out, (float*)d_out);
}